// Round 14
// baseline (132.632 us; speedup 1.0000x reference)
//
#include <hip/hip_runtime.h>

#define DD 128
#define NP 8
#define NK 4
#define NB 65536
#define COLS 64      // batch columns per block
#define PSTR 37      // odd stride for 36-float partial rows (conflict-free)
#define CST 136      // c_l row stride in bf16: 272B = 17*16 -> b128-aligned

typedef __bf16 bf16x8 __attribute__((ext_vector_type(8)));
typedef float  f32x4  __attribute__((ext_vector_type(4)));

// ---------------------------------------------------------------------------
// R13-verified kernel (114.7us, absmax 0.03125) with ONE numerics-identical
// change: pass-1 unroll 4 -> 8 (deeper load window; unrolling preserves the
// FP accumulation order, no fast-math -> bit-identical). Ledger: retention
// across phases spills (R8/R12); geometry changes break correctness
// (R9/R10/R11). This touches neither.
//
// LDS lifetime plan (single 37888B buffer, barrier-separated):
//   phase A (pass1 reduce+softmax): floats [0 .. 9472)    partials/reduced
//   phase B (LN1 stats exchange):   bytes  [18432..20480) sred[4][64][2]
//   phase C (c tile, bf16):         bytes  [0 .. 17408)   c_l[64][CST]
//   phase D (LN2 sums):             bytes  [20480..22528) sums2[4][64][2]
// ---------------------------------------------------------------------------
__global__ __launch_bounds__(256, 4) void fused_all(
    const float* __restrict__ q, const float* __restrict__ keys,
    const float* __restrict__ A,
    const float* __restrict__ g1, const float* __restrict__ b1,
    const float* __restrict__ W,  const float* __restrict__ Bv,
    const float* __restrict__ g2, const float* __restrict__ b2,
    float* __restrict__ out)
{
    __shared__ __align__(16) float lds[4 * COLS * PSTR];   // 37888 B
    __bf16* c_l        = (__bf16*)lds;                      // bytes 0..17407
    float (*sred)[COLS][2]  = (float (*)[COLS][2])((char*)lds + 18432);
    float (*sums2)[COLS][2] = (float (*)[COLS][2])((char*)lds + 20480);

    const int t   = threadIdx.x;
    const int col = t & 63;
    const int dg  = __builtin_amdgcn_readfirstlane(t >> 6);  // wave id 0..3
    const int gcol0 = blockIdx.x * COLS;
    const int b   = gcol0 + col;
    const int dbase = dg * 32;

    // ---- pass 1: partial dots over this wave's 32 d's --------------------
    float qd[NK] = {0.f, 0.f, 0.f, 0.f};
    float kd[NP][NK];
    #pragma unroll
    for (int n = 0; n < NP; ++n)
        #pragma unroll
        for (int k = 0; k < NK; ++k) kd[n][k] = 0.f;

    #pragma unroll 8
    for (int dd = 0; dd < 32; ++dd) {
        const int d = dbase + dd;                       // wave-uniform
        const float4 at = *(const float4*)(A + d * NK);        // s_load
        const float4 ab = *(const float4*)(A + (DD + d) * NK); // s_load
        const float qv = q[d * NB + b];
        qd[0] += qv * at.x; qd[1] += qv * at.y;
        qd[2] += qv * at.z; qd[3] += qv * at.w;
        #pragma unroll
        for (int n = 0; n < NP; ++n) {
            const float kv = keys[(n * DD + d) * NB + b];
            kd[n][0] += kv * ab.x; kd[n][1] += kv * ab.y;
            kd[n][2] += kv * ab.z; kd[n][3] += kv * ab.w;
        }
    }

    // ---- cross-wave reduce of the 36 partials (R7 verbatim) --------------
    {
        float* my = &lds[(dg * COLS + col) * PSTR];
        #pragma unroll
        for (int k = 0; k < NK; ++k) my[k] = qd[k];
        #pragma unroll
        for (int n = 0; n < NP; ++n)
            #pragma unroll
            for (int k = 0; k < NK; ++k) my[4 + n * NK + k] = kd[n][k];
    }
    __syncthreads();                                    // (1)
    #pragma unroll
    for (int ii = 0; ii < 9; ++ii) {
        const int i = dg * 9 + ii;
        float s = lds[(0 * COLS + col) * PSTR + i]
                + lds[(1 * COLS + col) * PSTR + i]
                + lds[(2 * COLS + col) * PSTR + i]
                + lds[(3 * COLS + col) * PSTR + i];
        lds[col * PSTR + i] = s;   // self-RAW only: safe
    }
    __syncthreads();                                    // (2)

    // ---- softmax over n (R7 verbatim) ------------------------------------
    float w[NP];
    {
        float z[NP][NK];
        float qs[NK];
        #pragma unroll
        for (int k = 0; k < NK; ++k) qs[k] = lds[col * PSTR + k];
        float mx[NK] = {-3.4e38f, -3.4e38f, -3.4e38f, -3.4e38f};
        #pragma unroll
        for (int n = 0; n < NP; ++n)
            #pragma unroll
            for (int k = 0; k < NK; ++k) {
                float v = qs[k] + lds[col * PSTR + 4 + n * NK + k];
                v = (v >= 0.f) ? v : 0.01f * v;     // leaky_relu
                z[n][k] = v;
                mx[k] = fmaxf(mx[k], v);
            }
        float S[NK] = {0.f, 0.f, 0.f, 0.f};
        #pragma unroll
        for (int n = 0; n < NP; ++n)
            #pragma unroll
            for (int k = 0; k < NK; ++k) {
                const float e = __expf(z[n][k] - mx[k]);
                z[n][k] = e;
                S[k] += e;
            }
        #pragma unroll
        for (int k = 0; k < NK; ++k) S[k] = 1.f / S[k];
        #pragma unroll
        for (int n = 0; n < NP; ++n)
            w[n] = 0.25f * (z[n][0] * S[0] + z[n][1] * S[1] +
                            z[n][2] * S[2] + z[n][3] * S[3]);
    }

    // ---- pass 2: weighted combine + relu + +q; y stays in registers ------
    float y[32];
    float sum = 0.f, ssq = 0.f;
    #pragma unroll 4
    for (int dd = 0; dd < 32; ++dd) {
        const int d = dbase + dd;
        float acc = 0.f;
        #pragma unroll
        for (int n = 0; n < NP; ++n) acc += w[n] * keys[(n * DD + d) * NB + b];
        const float yv = fmaxf(acc, 0.f) + q[d * NB + b];
        y[dd] = yv;
        sum += yv;
        ssq += yv * yv;
    }
    __syncthreads();   // (3) all softmax reads of lds[0..9472) are done
    sred[dg][col][0] = sum;
    sred[dg][col][1] = ssq;
    __syncthreads();   // (4) stats ready
    float ts1 = 0.f, tq1 = 0.f;
    #pragma unroll
    for (int g = 0; g < 4; ++g) {
        ts1 += sred[g][col][0];
        tq1 += sred[g][col][1];
    }
    const float mu = ts1 * (1.f / DD);
    const float rs = rsqrtf(tq1 * (1.f / DD) - mu * mu + 1e-6f);

    // ---- c = LN1(y) -> bf16 -> c_l tile (R7 verbatim) --------------------
    {
        bf16x8 cb[4];
        #pragma unroll
        for (int j = 0; j < 4; ++j)
            #pragma unroll
            for (int e = 0; e < 8; ++e) {
                const int d = dbase + j * 8 + e;        // wave-uniform
                cb[j][e] = (__bf16)(g1[d] * ((y[j * 8 + e] - mu) * rs) + b1[d]);
            }
        #pragma unroll
        for (int j = 0; j < 4; ++j)
            *(bf16x8*)(c_l + col * CST + dbase + j * 8) = cb[j];
    }
    __syncthreads();   // (5) c tile complete

    // ---- MFMA: wave dg -> rows dg*32..+31, cols 0..63 (R7 verbatim) ------
    const int lane = t & 63;
    const int c16  = lane & 15;
    const int dg4  = lane >> 4;

    bf16x8 wf[2][4];
    #pragma unroll
    for (int mi = 0; mi < 2; ++mi)
        #pragma unroll
        for (int kk = 0; kk < 4; ++kk) {
            const int row = dg * 32 + mi * 16 + c16;
            const int kb2 = kk * 32 + dg4 * 8;
            const float4 wa = *(const float4*)(W + row * DD + kb2);
            const float4 wb = *(const float4*)(W + row * DD + kb2 + 4);
            bf16x8 f;
            f[0] = (__bf16)wa.x; f[1] = (__bf16)wa.y;
            f[2] = (__bf16)wa.z; f[3] = (__bf16)wa.w;
            f[4] = (__bf16)wb.x; f[5] = (__bf16)wb.y;
            f[6] = (__bf16)wb.z; f[7] = (__bf16)wb.w;
            wf[mi][kk] = f;
        }

    f32x4 acc[2][4];
    #pragma unroll
    for (int mi = 0; mi < 2; ++mi)
        #pragma unroll
        for (int nf = 0; nf < 4; ++nf)
            acc[mi][nf] = (f32x4){0.f, 0.f, 0.f, 0.f};

    #pragma unroll
    for (int kk = 0; kk < 4; ++kk) {
        bf16x8 bfv[4];
        #pragma unroll
        for (int nf = 0; nf < 4; ++nf)
            bfv[nf] = *(const bf16x8*)(c_l + (nf * 16 + c16) * CST + kk * 32 + dg4 * 8);
        #pragma unroll
        for (int mi = 0; mi < 2; ++mi)
            #pragma unroll
            for (int nf = 0; nf < 4; ++nf)
                acc[mi][nf] = __builtin_amdgcn_mfma_f32_16x16x32_bf16(
                    wf[mi][kk], bfv[nf], acc[mi][nf], 0, 0, 0);
    }

    // ---- epilogue: +B +c, LN2 over 4 waves, store (R7 verbatim) ----------
    float Brow[2][4], grow[2][4], brow[2][4];
    #pragma unroll
    for (int mi = 0; mi < 2; ++mi)
        #pragma unroll
        for (int r = 0; r < 4; ++r) {
            const int row = dg * 32 + mi * 16 + dg4 * 4 + r;
            Brow[mi][r] = Bv[row];
            grow[mi][r] = g2[row];
            brow[mi][r] = b2[row];
        }

    float vv[2][4][4];
    float ps[4] = {0.f,0.f,0.f,0.f}, pq[4] = {0.f,0.f,0.f,0.f};
    #pragma unroll
    for (int nf = 0; nf < 4; ++nf) {
        const int cl = nf * 16 + c16;
        #pragma unroll
        for (int mi = 0; mi < 2; ++mi)
            #pragma unroll
            for (int r = 0; r < 4; ++r) {
                const int row = dg * 32 + mi * 16 + dg4 * 4 + r;
                const float cres = (float)c_l[cl * CST + row];
                const float v = acc[mi][nf][r] + Brow[mi][r] + cres;
                vv[mi][nf][r] = v;
                ps[nf] += v;
                pq[nf] += v * v;
            }
    }
    #pragma unroll
    for (int nf = 0; nf < 4; ++nf) {
        ps[nf] += __shfl_xor(ps[nf], 16); ps[nf] += __shfl_xor(ps[nf], 32);
        pq[nf] += __shfl_xor(pq[nf], 16); pq[nf] += __shfl_xor(pq[nf], 32);
    }
    if (dg4 == 0) {
        #pragma unroll
        for (int nf = 0; nf < 4; ++nf) {
            sums2[dg][nf * 16 + c16][0] = ps[nf];
            sums2[dg][nf * 16 + c16][1] = pq[nf];
        }
    }
    __syncthreads();   // (6) LN2 cross-wave sums ready

    #pragma unroll
    for (int nf = 0; nf < 4; ++nf) {
        const int cl = nf * 16 + c16;
        float ts = 0.f, tq = 0.f;
        #pragma unroll
        for (int g = 0; g < 4; ++g) {
            ts += sums2[g][cl][0];
            tq += sums2[g][cl][1];
        }
        const float mu2 = ts * (1.f / DD);
        const float rs2 = rsqrtf(tq * (1.f / DD) - mu2 * mu2 + 1e-6f);
        #pragma unroll
        for (int mi = 0; mi < 2; ++mi)
            #pragma unroll
            for (int r = 0; r < 4; ++r) {
                const int row = dg * 32 + mi * 16 + dg4 * 4 + r;
                out[row * NB + gcol0 + cl] =
                    grow[mi][r] * ((vv[mi][nf][r] - mu2) * rs2) + brow[mi][r];
            }
    }
}

extern "C" void kernel_launch(void* const* d_in, const int* in_sizes, int n_in,
                              void* d_out, int out_size, void* d_ws, size_t ws_size,
                              hipStream_t stream)
{
    const float* q    = (const float*)d_in[0];  // [1,128,65536]
    const float* keys = (const float*)d_in[1];  // [8,128,65536]
    const float* A    = (const float*)d_in[2];  // [256,4]
    const float* g1   = (const float*)d_in[3];
    const float* b1   = (const float*)d_in[4];
    const float* W    = (const float*)d_in[5];  // [128,128]
    const float* Bv   = (const float*)d_in[6];  // [128,1]
    const float* g2   = (const float*)d_in[7];
    const float* b2   = (const float*)d_in[8];
    float* out = (float*)d_out;                 // [128,65536]

    fused_all<<<NB / COLS, 256, 0, stream>>>(q, keys, A, g1, b1, W, Bv, g2, b2, out);
}

// Round 15
// 114.494 us; speedup vs baseline: 1.1584x; 1.1584x over previous
//
#include <hip/hip_runtime.h>

#define DD 128
#define NP 8
#define NK 4
#define NB 65536
#define COLS 64      // batch columns per block
#define PSTR 37      // odd stride for 36-float partial rows (conflict-free)
#define CST 136      // c_l row stride in bf16: 272B = 17*16 -> b128-aligned

typedef __bf16 bf16x8 __attribute__((ext_vector_type(8)));
typedef float  f32x4  __attribute__((ext_vector_type(4)));

// ---------------------------------------------------------------------------
// FINAL: R7/R13-verified kernel (114.7us, absmax 0.03125, VGPR 56).
// Fully fused: attention weights -> combine -> LN1 -> bf16 c tile -> MFMA
// W@c -> +B +c -> LN2 -> out.  One HBM pass over q/keys (pass-2 re-read is
// L3-served); y/mu/rs never touch global.
//
// Experiment ledger (why this exact form):
//   - unroll 4 is the spill boundary: unroll 8 -> VGPR 64 + 26MB spill
//     traffic, +16% time (R14). Register retention across phases (qv/kb)
//     spills catastrophically (R8, R12).
//   - COLS=64/4-wave geometry is the verified one; COLS=32 and 8-wave
//     variants produced unlocalizable threshold-scale errors (R9-R11).
//   - Occupancy is grid-capped at 16 waves/CU; LDS shrink alone can't help.
//
// LDS lifetime plan (single 37888B buffer, barrier-separated):
//   phase A (pass1 reduce+softmax): floats [0 .. 9472)    partials/reduced
//   phase B (LN1 stats exchange):   bytes  [18432..20480) sred[4][64][2]
//   phase C (c tile, bf16):         bytes  [0 .. 17408)   c_l[64][CST]
//   phase D (LN2 sums):             bytes  [20480..22528) sums2[4][64][2]
// ---------------------------------------------------------------------------
__global__ __launch_bounds__(256, 4) void fused_all(
    const float* __restrict__ q, const float* __restrict__ keys,
    const float* __restrict__ A,
    const float* __restrict__ g1, const float* __restrict__ b1,
    const float* __restrict__ W,  const float* __restrict__ Bv,
    const float* __restrict__ g2, const float* __restrict__ b2,
    float* __restrict__ out)
{
    __shared__ __align__(16) float lds[4 * COLS * PSTR];   // 37888 B
    __bf16* c_l        = (__bf16*)lds;                      // bytes 0..17407
    float (*sred)[COLS][2]  = (float (*)[COLS][2])((char*)lds + 18432);
    float (*sums2)[COLS][2] = (float (*)[COLS][2])((char*)lds + 20480);

    const int t   = threadIdx.x;
    const int col = t & 63;
    const int dg  = __builtin_amdgcn_readfirstlane(t >> 6);  // wave id 0..3
    const int gcol0 = blockIdx.x * COLS;
    const int b   = gcol0 + col;
    const int dbase = dg * 32;

    // ---- pass 1: partial dots over this wave's 32 d's --------------------
    float qd[NK] = {0.f, 0.f, 0.f, 0.f};
    float kd[NP][NK];
    #pragma unroll
    for (int n = 0; n < NP; ++n)
        #pragma unroll
        for (int k = 0; k < NK; ++k) kd[n][k] = 0.f;

    #pragma unroll 4
    for (int dd = 0; dd < 32; ++dd) {
        const int d = dbase + dd;                       // wave-uniform
        const float4 at = *(const float4*)(A + d * NK);        // s_load
        const float4 ab = *(const float4*)(A + (DD + d) * NK); // s_load
        const float qv = q[d * NB + b];
        qd[0] += qv * at.x; qd[1] += qv * at.y;
        qd[2] += qv * at.z; qd[3] += qv * at.w;
        #pragma unroll
        for (int n = 0; n < NP; ++n) {
            const float kv = keys[(n * DD + d) * NB + b];
            kd[n][0] += kv * ab.x; kd[n][1] += kv * ab.y;
            kd[n][2] += kv * ab.z; kd[n][3] += kv * ab.w;
        }
    }

    // ---- cross-wave reduce of the 36 partials ----------------------------
    {
        float* my = &lds[(dg * COLS + col) * PSTR];
        #pragma unroll
        for (int k = 0; k < NK; ++k) my[k] = qd[k];
        #pragma unroll
        for (int n = 0; n < NP; ++n)
            #pragma unroll
            for (int k = 0; k < NK; ++k) my[4 + n * NK + k] = kd[n][k];
    }
    __syncthreads();                                    // (1)
    #pragma unroll
    for (int ii = 0; ii < 9; ++ii) {
        const int i = dg * 9 + ii;
        float s = lds[(0 * COLS + col) * PSTR + i]
                + lds[(1 * COLS + col) * PSTR + i]
                + lds[(2 * COLS + col) * PSTR + i]
                + lds[(3 * COLS + col) * PSTR + i];
        lds[col * PSTR + i] = s;   // self-RAW only: safe
    }
    __syncthreads();                                    // (2)

    // ---- softmax over n ---------------------------------------------------
    float w[NP];
    {
        float z[NP][NK];
        float qs[NK];
        #pragma unroll
        for (int k = 0; k < NK; ++k) qs[k] = lds[col * PSTR + k];
        float mx[NK] = {-3.4e38f, -3.4e38f, -3.4e38f, -3.4e38f};
        #pragma unroll
        for (int n = 0; n < NP; ++n)
            #pragma unroll
            for (int k = 0; k < NK; ++k) {
                float v = qs[k] + lds[col * PSTR + 4 + n * NK + k];
                v = (v >= 0.f) ? v : 0.01f * v;     // leaky_relu
                z[n][k] = v;
                mx[k] = fmaxf(mx[k], v);
            }
        float S[NK] = {0.f, 0.f, 0.f, 0.f};
        #pragma unroll
        for (int n = 0; n < NP; ++n)
            #pragma unroll
            for (int k = 0; k < NK; ++k) {
                const float e = __expf(z[n][k] - mx[k]);
                z[n][k] = e;
                S[k] += e;
            }
        #pragma unroll
        for (int k = 0; k < NK; ++k) S[k] = 1.f / S[k];
        #pragma unroll
        for (int n = 0; n < NP; ++n)
            w[n] = 0.25f * (z[n][0] * S[0] + z[n][1] * S[1] +
                            z[n][2] * S[2] + z[n][3] * S[3]);
    }

    // ---- pass 2: weighted combine + relu + +q; y stays in registers ------
    float y[32];
    float sum = 0.f, ssq = 0.f;
    #pragma unroll 4
    for (int dd = 0; dd < 32; ++dd) {
        const int d = dbase + dd;
        float acc = 0.f;
        #pragma unroll
        for (int n = 0; n < NP; ++n) acc += w[n] * keys[(n * DD + d) * NB + b];
        const float yv = fmaxf(acc, 0.f) + q[d * NB + b];
        y[dd] = yv;
        sum += yv;
        ssq += yv * yv;
    }
    __syncthreads();   // (3) all softmax reads of lds[0..9472) are done
    sred[dg][col][0] = sum;
    sred[dg][col][1] = ssq;
    __syncthreads();   // (4) stats ready
    float ts1 = 0.f, tq1 = 0.f;
    #pragma unroll
    for (int g = 0; g < 4; ++g) {
        ts1 += sred[g][col][0];
        tq1 += sred[g][col][1];
    }
    const float mu = ts1 * (1.f / DD);
    const float rs = rsqrtf(tq1 * (1.f / DD) - mu * mu + 1e-6f);

    // ---- c = LN1(y) -> bf16 -> c_l tile ----------------------------------
    {
        bf16x8 cb[4];
        #pragma unroll
        for (int j = 0; j < 4; ++j)
            #pragma unroll
            for (int e = 0; e < 8; ++e) {
                const int d = dbase + j * 8 + e;        // wave-uniform
                cb[j][e] = (__bf16)(g1[d] * ((y[j * 8 + e] - mu) * rs) + b1[d]);
            }
        #pragma unroll
        for (int j = 0; j < 4; ++j)
            *(bf16x8*)(c_l + col * CST + dbase + j * 8) = cb[j];
    }
    __syncthreads();   // (5) c tile complete

    // ---- MFMA: wave dg -> rows dg*32..+31, cols 0..63 --------------------
    const int lane = t & 63;
    const int c16  = lane & 15;
    const int dg4  = lane >> 4;

    bf16x8 wf[2][4];
    #pragma unroll
    for (int mi = 0; mi < 2; ++mi)
        #pragma unroll
        for (int kk = 0; kk < 4; ++kk) {
            const int row = dg * 32 + mi * 16 + c16;
            const int kb2 = kk * 32 + dg4 * 8;
            const float4 wa = *(const float4*)(W + row * DD + kb2);
            const float4 wb = *(const float4*)(W + row * DD + kb2 + 4);
            bf16x8 f;
            f[0] = (__bf16)wa.x; f[1] = (__bf16)wa.y;
            f[2] = (__bf16)wa.z; f[3] = (__bf16)wa.w;
            f[4] = (__bf16)wb.x; f[5] = (__bf16)wb.y;
            f[6] = (__bf16)wb.z; f[7] = (__bf16)wb.w;
            wf[mi][kk] = f;
        }

    f32x4 acc[2][4];
    #pragma unroll
    for (int mi = 0; mi < 2; ++mi)
        #pragma unroll
        for (int nf = 0; nf < 4; ++nf)
            acc[mi][nf] = (f32x4){0.f, 0.f, 0.f, 0.f};

    #pragma unroll
    for (int kk = 0; kk < 4; ++kk) {
        bf16x8 bfv[4];
        #pragma unroll
        for (int nf = 0; nf < 4; ++nf)
            bfv[nf] = *(const bf16x8*)(c_l + (nf * 16 + c16) * CST + kk * 32 + dg4 * 8);
        #pragma unroll
        for (int mi = 0; mi < 2; ++mi)
            #pragma unroll
            for (int nf = 0; nf < 4; ++nf)
                acc[mi][nf] = __builtin_amdgcn_mfma_f32_16x16x32_bf16(
                    wf[mi][kk], bfv[nf], acc[mi][nf], 0, 0, 0);
    }

    // ---- epilogue: +B +c, LN2 over 4 waves, store ------------------------
    float Brow[2][4], grow[2][4], brow[2][4];
    #pragma unroll
    for (int mi = 0; mi < 2; ++mi)
        #pragma unroll
        for (int r = 0; r < 4; ++r) {
            const int row = dg * 32 + mi * 16 + dg4 * 4 + r;
            Brow[mi][r] = Bv[row];
            grow[mi][r] = g2[row];
            brow[mi][r] = b2[row];
        }

    float vv[2][4][4];
    float ps[4] = {0.f,0.f,0.f,0.f}, pq[4] = {0.f,0.f,0.f,0.f};
    #pragma unroll
    for (int nf = 0; nf < 4; ++nf) {
        const int cl = nf * 16 + c16;
        #pragma unroll
        for (int mi = 0; mi < 2; ++mi)
            #pragma unroll
            for (int r = 0; r < 4; ++r) {
                const int row = dg * 32 + mi * 16 + dg4 * 4 + r;
                const float cres = (float)c_l[cl * CST + row];
                const float v = acc[mi][nf][r] + Brow[mi][r] + cres;
                vv[mi][nf][r] = v;
                ps[nf] += v;
                pq[nf] += v * v;
            }
    }
    #pragma unroll
    for (int nf = 0; nf < 4; ++nf) {
        ps[nf] += __shfl_xor(ps[nf], 16); ps[nf] += __shfl_xor(ps[nf], 32);
        pq[nf] += __shfl_xor(pq[nf], 16); pq[nf] += __shfl_xor(pq[nf], 32);
    }
    if (dg4 == 0) {
        #pragma unroll
        for (int nf = 0; nf < 4; ++nf) {
            sums2[dg][nf * 16 + c16][0] = ps[nf];
            sums2[dg][nf * 16 + c16][1] = pq[nf];
        }
    }
    __syncthreads();   // (6) LN2 cross-wave sums ready

    #pragma unroll
    for (int nf = 0; nf < 4; ++nf) {
        const int cl = nf * 16 + c16;
        float ts = 0.f, tq = 0.f;
        #pragma unroll
        for (int g = 0; g < 4; ++g) {
            ts += sums2[g][cl][0];
            tq += sums2[g][cl][1];
        }
        const float mu2 = ts * (1.f / DD);
        const float rs2 = rsqrtf(tq * (1.f / DD) - mu2 * mu2 + 1e-6f);
        #pragma unroll
        for (int mi = 0; mi < 2; ++mi)
            #pragma unroll
            for (int r = 0; r < 4; ++r) {
                const int row = dg * 32 + mi * 16 + dg4 * 4 + r;
                out[row * NB + gcol0 + cl] =
                    grow[mi][r] * ((vv[mi][nf][r] - mu2) * rs2) + brow[mi][r];
            }
    }
}

extern "C" void kernel_launch(void* const* d_in, const int* in_sizes, int n_in,
                              void* d_out, int out_size, void* d_ws, size_t ws_size,
                              hipStream_t stream)
{
    const float* q    = (const float*)d_in[0];  // [1,128,65536]
    const float* keys = (const float*)d_in[1];  // [8,128,65536]
    const float* A    = (const float*)d_in[2];  // [256,4]
    const float* g1   = (const float*)d_in[3];
    const float* b1   = (const float*)d_in[4];
    const float* W    = (const float*)d_in[5];  // [128,128]
    const float* Bv   = (const float*)d_in[6];  // [128,1]
    const float* g2   = (const float*)d_in[7];
    const float* b2   = (const float*)d_in[8];
    float* out = (float*)d_out;                 // [128,65536]

    fused_all<<<NB / COLS, 256, 0, stream>>>(q, keys, A, g1, b1, W, Bv, g2, b2, out);
}